// Round 1
// baseline (141.570 us; speedup 1.0000x reference)
//
#include <hip/hip_runtime.h>
#include <math.h>

#define BB 1024
#define NN 256
#define VV 200
#define BT 8          // batch rows per k_final tile
#define NSH 16        // BN-stat atomic shards
#define RPB 4         // rows per block in k_attn (one per wave)

// d_ws layout (floats):
//   [0    .. 256)        g_M   (245 used: up[98] | dn[98]@98 | pv[49]@196)
//   [256  .. 256+19200)  stats: g_sum[NSH][600] then g_ss[NSH][600]
//   [19456.. +614400)  g_x [3][1024][200]
#define WS_M    0
#define WS_STAT 256
#define WS_X    19456

// ---------------- K0: M = Wq @ Wk^T (blocks 0-2) + zero stats/out (all 8 blocks) ----------------
__global__ __launch_bounds__(256) void k_prep(const float* __restrict__ upWq, const float* __restrict__ upWk,
                                              const float* __restrict__ dnWq, const float* __restrict__ dnWk,
                                              const float* __restrict__ pvWq, const float* __restrict__ pvWk,
                                              float* __restrict__ ws, float* __restrict__ out) {
    __shared__ float wq[7 * VV];
    __shared__ float wk[14 * VV];
    int blk = blockIdx.x, tid = threadIdx.x;
    float* stat = ws + WS_STAT;
    for (int i = blk * 256 + tid; i < 2 * NSH * 600; i += 8 * 256) stat[i] = 0.f;
    for (int i = blk * 256 + tid; i < BB; i += 8 * 256) out[i] = 0.f;

    if (blk < 3) {
        const float* Wq = blk == 0 ? upWq : (blk == 1 ? dnWq : pvWq);
        const float* Wk = blk == 0 ? upWk : (blk == 1 ? dnWk : pvWk);
        int F = (blk == 2) ? 7 : 14;
        int off = blk == 0 ? 0 : (blk == 1 ? 98 : 196);
        for (int i = tid; i < 7 * VV; i += 256) wq[i] = Wq[i];
        for (int i = tid; i < F * VV; i += 256) wk[i] = Wk[i];
        __syncthreads();
        if (tid < 7 * F) {
            int i = tid / F, f = tid % F;
            float s = 0.f;
            for (int v = 0; v < VV; v++) s += wq[i * VV + v] * wk[f * VV + v];
            ws[WS_M + off + tid] = s;   // layout: [h] i*F + f
        }
    }
}

// ---------------- K1: attention — ONE ROW PER WAVE (grid 256, 4 rows/block) ----------------
// Lane owns positions {lane, lane+64, lane+128, lane+192} with features in registers.
// Softmax via intra-wave shuffle butterflies: NO block-wide barriers on the critical path.
// BN stats: LDS-atomic block combine (4 rows), then 1200 global atomics per block (4x fewer).
__global__ __launch_bounds__(256, 1) void k_attn(
    const float* __restrict__ merged, const float* __restrict__ a,
    const float* __restrict__ upWv, const float* __restrict__ dnWv, const float* __restrict__ pvWv,
    float* __restrict__ ws) {
    int tid = threadIdx.x;
    int lane = tid & 63, wave = tid >> 6;
    int b = blockIdx.x * RPB + wave;

    __shared__ float eMsh[RPB][35];
    __shared__ float csh[RPB][35];
    __shared__ float partsh[RPB][64 * 37 + 1];   // stride-37: conflict-free transpose
    __shared__ float ssum[600], sss[600];        // block-local BN-stat accumulators

    const float* gM = ws + WS_M;
    float* g_sum = ws + WS_STAT;
    float* g_ss  = ws + WS_STAT + NSH * 600;
    float* g_x   = ws + WS_X;

    for (int i = tid; i < 600; i += 256) { ssum[i] = 0.f; sss[i] = 0.f; }
    __syncthreads();

    const float* row = merged + (size_t)b * (NN * 15);
    float ab = a[b];
    float subj_id  = row[0];
    float e1v      = row[1];
    float subj_loc = row[2];
    float e3v = row[3], e4v = row[4], e5v = row[5];

    // ---- per-lane features (registers) ----
    float ft[4][15];
#pragma unroll
    for (int j = 0; j < 4; j++) {
        const float* r = row + (lane + 64 * j) * 15;
#pragma unroll
        for (int c = 0; c < 15; c++) ft[j][c] = r[c];
    }
#pragma unroll
    for (int j = 0; j < 4; j++) { ft[j][0] -= subj_id; ft[j][7] -= subj_id; }
    if (lane == 0) ft[0][6] = ab;   // merged[:,0,6] = a  (position 0 lives on lane 0, j 0)

    // ---- eM[35] = ego @ M  (lanes 0..34; ego[0]==0 so start at i=1) ----
    if (lane < 35) {
        int h = lane < 14 ? 0 : (lane < 28 ? 1 : 2);
        int f = lane - (h == 0 ? 0 : (h == 1 ? 14 : 28));
        int F = (h == 2) ? 7 : 14;
        const float* M = gM + (h == 0 ? 0 : (h == 1 ? 98 : 196));
        eMsh[wave][f + (h == 0 ? 0 : (h == 1 ? 14 : 28))] =
            e1v * M[1 * F + f] + subj_loc * M[2 * F + f] + e3v * M[3 * F + f] +
            e4v * M[4 * F + f] + e5v * M[5 * F + f] + ab * M[6 * F + f];
    }
    asm volatile("s_waitcnt lgkmcnt(0)" ::: "memory");   // in-wave LDS handoff (rule #18)
    __builtin_amdgcn_sched_barrier(0);

    float eM[35];
#pragma unroll
    for (int f = 0; f < 35; f++) eM[f] = eMsh[wave][f];

    // ---- scores + masks ----
    const float scale = 7.0710678118654752e-2f;  // 1/sqrt(200)
    float s0[4], s1[4], s2[4];
#pragma unroll
    for (int j = 0; j < 4; j++) {
        float a0 = 0.f, a1 = 0.f, a2 = 0.f;
#pragma unroll
        for (int f = 0; f < 14; f++) { a0 += eM[f] * ft[j][f]; a1 += eM[14 + f] * ft[j][f]; }
#pragma unroll
        for (int f = 0; f < 7; f++) a2 += eM[28 + f] * ft[j][f];
        float loc = ft[j][2], flag = ft[j][14];
        s0[j] = ((loc < subj_loc) && (flag == 1.f)) ? a0 * scale : -1e9f;
        s1[j] = ((loc > subj_loc) && (flag == 1.f)) ? a1 * scale : -1e9f;
        s2[j] = (flag == 0.f) ? a2 * scale : -1e9f;
    }

    // ---- softmax: pure wave butterflies ----
    float m0 = fmaxf(fmaxf(s0[0], s0[1]), fmaxf(s0[2], s0[3]));
    float m1 = fmaxf(fmaxf(s1[0], s1[1]), fmaxf(s1[2], s1[3]));
    float m2 = fmaxf(fmaxf(s2[0], s2[1]), fmaxf(s2[2], s2[3]));
#pragma unroll
    for (int off = 32; off; off >>= 1) {
        m0 = fmaxf(m0, __shfl_xor(m0, off));
        m1 = fmaxf(m1, __shfl_xor(m1, off));
        m2 = fmaxf(m2, __shfl_xor(m2, off));
    }
    float p0[4], p1[4], p2[4];
    float z0 = 0.f, z1 = 0.f, z2 = 0.f;
#pragma unroll
    for (int j = 0; j < 4; j++) {
        p0[j] = expf(s0[j] - m0); z0 += p0[j];
        p1[j] = expf(s1[j] - m1); z1 += p1[j];
        p2[j] = expf(s2[j] - m2); z2 += p2[j];
    }
#pragma unroll
    for (int off = 32; off; off >>= 1) {
        z0 += __shfl_xor(z0, off);
        z1 += __shfl_xor(z1, off);
        z2 += __shfl_xor(z2, off);
    }
    float iz0 = 1.f / z0, iz1 = 1.f / z1, iz2 = 1.f / z2;
#pragma unroll
    for (int j = 0; j < 4; j++) { p0[j] *= iz0; p1[j] *= iz1; p2[j] *= iz2; }

    // ---- c[h][f]: per-lane partials over 4 positions, LDS-transpose reduce ----
    float pt[35];
#pragma unroll
    for (int f = 0; f < 14; f++)
        pt[f] = p0[0] * ft[0][f] + p0[1] * ft[1][f] + p0[2] * ft[2][f] + p0[3] * ft[3][f];
#pragma unroll
    for (int f = 0; f < 14; f++)
        pt[14 + f] = p1[0] * ft[0][f] + p1[1] * ft[1][f] + p1[2] * ft[2][f] + p1[3] * ft[3][f];
#pragma unroll
    for (int f = 0; f < 7; f++)
        pt[28 + f] = p2[0] * ft[0][f] + p2[1] * ft[1][f] + p2[2] * ft[2][f] + p2[3] * ft[3][f];

    {
        float* pb = &partsh[wave][lane * 37];
#pragma unroll
        for (int d = 0; d < 35; d++) pb[d] = pt[d];
    }
    asm volatile("s_waitcnt lgkmcnt(0)" ::: "memory");
    __builtin_amdgcn_sched_barrier(0);
    if (lane < 35) {
        const float* ps = &partsh[wave][lane];
        float c = 0.f;
#pragma unroll
        for (int l = 0; l < 64; l++) c += ps[l * 37];
        csh[wave][lane] = c;
    }
    asm volatile("s_waitcnt lgkmcnt(0)" ::: "memory");
    __builtin_amdgcn_sched_barrier(0);

    float cc[35];
#pragma unroll
    for (int d = 0; d < 35; d++) cc[d] = csh[wave][d];

    // ---- projection: lane covers v = lane + 64*vi; store g_x + LDS-atomic stats ----
#pragma unroll
    for (int vi = 0; vi < 4; vi++) {
        int v = lane + 64 * vi;
        if (v < VV) {
            float v0 = 0.f, v1 = 0.f, v2 = 0.f;
#pragma unroll
            for (int f = 0; f < 14; f++) { v0 += cc[f] * upWv[f * VV + v]; v1 += cc[14 + f] * dnWv[f * VV + v]; }
#pragma unroll
            for (int f = 0; f < 7; f++) v2 += cc[28 + f] * pvWv[f * VV + v];
            if (m0 == -1e9f) v0 = 0.f;
            if (m1 == -1e9f) v1 = 0.f;
            if (m2 == -1e9f) v2 = 0.f;
            g_x[((size_t)0 * BB + b) * VV + v] = v0;
            g_x[((size_t)1 * BB + b) * VV + v] = v1;
            g_x[((size_t)2 * BB + b) * VV + v] = v2;
            atomicAdd(&ssum[v], v0);            atomicAdd(&sss[v], v0 * v0);
            atomicAdd(&ssum[VV + v], v1);       atomicAdd(&sss[VV + v], v1 * v1);
            atomicAdd(&ssum[2 * VV + v], v2);   atomicAdd(&sss[2 * VV + v], v2 * v2);
        }
    }

    // ---- flush block-combined stats: 1200 global atomics per block ----
    __syncthreads();
    int shard = blockIdx.x & (NSH - 1);
    for (int i = tid; i < 600; i += 256) {
        atomicAdd(&g_sum[shard * 600 + i], ssum[i]);
        atomicAdd(&g_ss[shard * 600 + i], sss[i]);
    }
}

// ---------------- K2: BN finalize+apply + trunk GEMM / e-MLP (R4 structure) ----------------
// grid = 128 tiles * 4 groups (BT=8 rows). q<3: trunk head q. q==3: e-MLP.
__global__ __launch_bounds__(256) void k_final(const float* __restrict__ merged, const float* __restrict__ a,
                                               const float* __restrict__ tW1, const float* __restrict__ tb1,
                                               const float* __restrict__ tW2, const float* __restrict__ tb2,
                                               const float* __restrict__ eW1, const float* __restrict__ eb1,
                                               const float* __restrict__ eW2, const float* __restrict__ eb2,
                                               const float* __restrict__ eW3, const float* __restrict__ eb3,
                                               const float* __restrict__ gamma, const float* __restrict__ beta,
                                               const float* __restrict__ ws,
                                               float* __restrict__ out) {
    int tile = blockIdx.x >> 2;
    int q = blockIdx.x & 3;
    int b0 = tile * BT;
    int tid = threadIdx.x;
    int lane = tid & 63, wave = tid >> 6;
    int w = tid;

    __shared__ __align__(16) float tT[VV * BT];  // [v][bb]
    __shared__ float redsh[4 * BT];
    __shared__ float esh[BT][4];

    const float* g_sum = ws + WS_STAT;
    const float* g_ss  = ws + WS_STAT + NSH * 600;
    const float* g_x   = ws + WS_X;

    float fin[BT];
#pragma unroll
    for (int bb = 0; bb < BT; bb++) fin[bb] = 0.f;

    if (q < 3) {
        __shared__ float bnA[VV], bnB[VV];
        if (w < VV) {
            float S = 0.f, S2 = 0.f;
#pragma unroll
            for (int s = 0; s < NSH; s++) {
                S += g_sum[s * 600 + q * VV + w];
                S2 += g_ss[s * 600 + q * VV + w];
            }
            float m = S * (1.f / BB);
            float var = S2 * (1.f / BB) - m * m;
            float rstd = rsqrtf(var + 1e-5f);
            float gv = gamma[w];
            bnA[w] = gv * rstd;
            bnB[w] = beta[w] - gv * rstd * m;
        }
        __syncthreads();
        for (int idx = tid; idx < BT * VV; idx += 256) {
            int v = idx % VV, bb = idx / VV;
            float val = g_x[((size_t)q * BB + b0 + bb) * VV + v];
            tT[v * BT + bb] = bnA[v] * val + bnB[v];
        }
        __syncthreads();

        if (w < VV) {
            float acc[BT];
            float bias = tb1[q * VV + w];
#pragma unroll
            for (int bb = 0; bb < BT; bb++) acc[bb] = bias;
            const float* W1 = tW1 + (size_t)q * VV * VV + w;
            const float4* tT4 = (const float4*)tT;
#pragma unroll 8
            for (int v = 0; v < VV; v++) {
                float w1 = W1[(size_t)v * VV];
                float4 t0 = tT4[v * 2 + 0];
                float4 t1 = tT4[v * 2 + 1];
                acc[0] += t0.x * w1; acc[1] += t0.y * w1; acc[2] += t0.z * w1; acc[3] += t0.w * w1;
                acc[4] += t1.x * w1; acc[5] += t1.y * w1; acc[6] += t1.z * w1; acc[7] += t1.w * w1;
            }
            float w2 = tW2[q * VV + w];
#pragma unroll
            for (int bb = 0; bb < BT; bb++) {
                float h = acc[bb];
                h = h > 0.f ? h : expf(h) - 1.f;   // ELU
                fin[bb] = h * w2;
            }
        }
    } else {
        if (tid < BT) {
            const float* mrow = merged + (size_t)(b0 + tid) * NN * 15;
            esh[tid][0] = mrow[3];
            esh[tid][1] = mrow[4];
            esh[tid][2] = mrow[5];
            esh[tid][3] = a[b0 + tid];
        }
        __syncthreads();
        if (w < VV) {
            float e0 = eW1[w], e1 = eW1[VV + w], e2 = eW1[2 * VV + w], e3 = eW1[3 * VV + w];
            float bias = eb1[w];
#pragma unroll
            for (int bb = 0; bb < BT; bb++) {
                float qv = bias + esh[bb][0] * e0 + esh[bb][1] * e1 + esh[bb][2] * e2 + esh[bb][3] * e3;
                tT[w * BT + bb] = fmaxf(qv, 0.f);
            }
        }
        __syncthreads();
        if (w < VV) {
            float acc[BT];
            float bias = eb2[w];
#pragma unroll
            for (int bb = 0; bb < BT; bb++) acc[bb] = bias;
            const float* W2 = eW2 + w;
            const float4* tT4 = (const float4*)tT;
#pragma unroll 8
            for (int v = 0; v < VV; v++) {
                float w2v = W2[(size_t)v * VV];
                float4 t0 = tT4[v * 2 + 0];
                float4 t1 = tT4[v * 2 + 1];
                acc[0] += t0.x * w2v; acc[1] += t0.y * w2v; acc[2] += t0.z * w2v; acc[3] += t0.w * w2v;
                acc[4] += t1.x * w2v; acc[5] += t1.y * w2v; acc[6] += t1.z * w2v; acc[7] += t1.w * w2v;
            }
            float w3 = eW3[w];
#pragma unroll
            for (int bb = 0; bb < BT; bb++) fin[bb] = fmaxf(acc[bb], 0.f) * w3;
        }
    }

#pragma unroll
    for (int bb = 0; bb < BT; bb++)
#pragma unroll
        for (int off = 32; off; off >>= 1) fin[bb] += __shfl_xor(fin[bb], off);
    if (lane == 0)
#pragma unroll
        for (int bb = 0; bb < BT; bb++) redsh[wave * BT + bb] = fin[bb];
    __syncthreads();
    if (tid < BT) {
        float tot = redsh[tid] + redsh[BT + tid] + redsh[2 * BT + tid] + redsh[3 * BT + tid];
        if (q == 3) tot += eb3[0] + tb2[0] + tb2[1] + tb2[2];
        atomicAdd(&out[b0 + tid], tot);
    }
}

extern "C" void kernel_launch(void* const* d_in, const int* in_sizes, int n_in,
                              void* d_out, int out_size, void* d_ws, size_t ws_size,
                              hipStream_t stream) {
    const float* merged = (const float*)d_in[0];
    const float* a      = (const float*)d_in[1];
    const float* upWq   = (const float*)d_in[2];
    const float* upWk   = (const float*)d_in[3];
    const float* upWv   = (const float*)d_in[4];
    const float* dnWq   = (const float*)d_in[5];
    const float* dnWk   = (const float*)d_in[6];
    const float* dnWv   = (const float*)d_in[7];
    const float* pvWq   = (const float*)d_in[8];
    const float* pvWk   = (const float*)d_in[9];
    const float* pvWv   = (const float*)d_in[10];
    const float* tW1    = (const float*)d_in[11];
    const float* tb1    = (const float*)d_in[12];
    const float* tW2    = (const float*)d_in[13];
    const float* tb2    = (const float*)d_in[14];
    const float* eW1    = (const float*)d_in[15];
    const float* eb1    = (const float*)d_in[16];
    const float* eW2    = (const float*)d_in[17];
    const float* eb2    = (const float*)d_in[18];
    const float* eW3    = (const float*)d_in[19];
    const float* eb3    = (const float*)d_in[20];
    const float* gamma  = (const float*)d_in[21];
    const float* beta   = (const float*)d_in[22];
    float* out = (float*)d_out;
    float* ws = (float*)d_ws;

    hipLaunchKernelGGL(k_prep, dim3(8), dim3(256), 0, stream, upWq, upWk, dnWq, dnWk, pvWq, pvWk, ws, out);
    hipLaunchKernelGGL(k_attn, dim3(BB / RPB), dim3(256), 0, stream, merged, a, upWv, dnWv, pvWv, ws);
    hipLaunchKernelGGL(k_final, dim3((BB / BT) * 4), dim3(256), 0, stream, merged, a,
                       tW1, tb1, tW2, tb2, eW1, eb1, eW2, eb2, eW3, eb3, gamma, beta, ws, out);
}